// Round 8
// baseline (151.457 us; speedup 1.0000x reference)
//
#include <hip/hip_runtime.h>

// Reinsertion: B=32, G=512, D=128, H=4, KD=32. Output (B,G,G) fp32.
//
// R8: R6 wave-structure (2 chunks of 32 g2 per wave, 16 g1 iters, grid
// (2,32,32)) + R7 fused stage01 + two cuts in mlp_pairs:
//  - epilogue on float2 -> v_pk_max_f32 / v_pk_fma_f32 (halves epilogue)
//  - single shfl_xor(32) serves both chunks via select-swap; full-wave store.

#define B 32
#define G 512
#define D 128
#define NH 4
#define KD 32
#define NORMF 0.17677669529663687f  // 1/sqrt(32)

// ws: fp16 P/Q only (half-indices)
#define WS_P16H 131072
#define WS_Q16H 655360

typedef float v16f __attribute__((ext_vector_type(16)));
typedef float f2v __attribute__((ext_vector_type(2)));
typedef _Float16 v8h __attribute__((ext_vector_type(8)));
typedef _Float16 h2v __attribute__((ext_vector_type(2)));

struct HQ { h2v h[4]; };   // 8 halves = 4 VGPRs
struct F2x8 { f2v v[8]; }; // 16 floats as 8 packed pairs

__device__ __forceinline__ v8h relu_add(const HQ& p, const HQ& q) {
  const h2v z = {(_Float16)0.0f, (_Float16)0.0f};
  HQ r;
#pragma unroll
  for (int i = 0; i < 4; ++i)
    r.h[i] = __builtin_elementwise_max(p.h[i] + q.h[i], z);
  return __builtin_bit_cast(v8h, r);
}

// ---------------- Stage 0+1 fused: A-tables (LDS) + P/Q vectors ----------------
__global__ __launch_bounds__(256) void stage01(
    const float* __restrict__ h, const int* __restrict__ pp,
    const int* __restrict__ pd, const int* __restrict__ rec,
    const float* __restrict__ Wq1, const float* __restrict__ Wk1,
    const float* __restrict__ Wq2, const float* __restrict__ Wk2,
    const float* __restrict__ fc1_w, const float* __restrict__ fc1_b,
    float* __restrict__ ws) {
  const int bx = blockIdx.x;
  const int b = bx >> 3, g0 = (bx & 7) * 64;
  const int t = threadIdx.x;

  __shared__ float hp[D], hd[D];
  __shared__ float qq[4][NH * KD];   // q1p,q2p,q1d,q2d
  __shared__ float sA[4][NH][D];     // Apq,Apo,Adp,Ado
  __shared__ float sc[64][17];
  __shared__ float sout[64][33];

  if (t < 128) {
    hp[t] = h[((size_t)b * G + pp[b]) * D + t];
  } else {
    const int u = t - 128;
    hd[u] = h[((size_t)b * G + pd[b]) * D + u];
  }
  __syncthreads();

  if (t < 128) {  // t -> (head hh, key k); dot over d
    const int hh = t >> 5, k = t & 31;
    const float* wq1 = Wq1 + hh * D * KD + k;
    const float* wq2 = Wq2 + hh * D * KD + k;
    float s1p = 0.f, s2p = 0.f, s1d = 0.f, s2d = 0.f;
    for (int d = 0; d < D; ++d) {
      const float w1 = wq1[d * KD], w2 = wq2[d * KD];
      const float xp = hp[d], xd = hd[d];
      s1p = fmaf(xp, w1, s1p);
      s2p = fmaf(xp, w2, s2p);
      s1d = fmaf(xd, w1, s1d);
      s2d = fmaf(xd, w2, s2d);
    }
    qq[0][t] = s1p; qq[1][t] = s2p; qq[2][t] = s1d; qq[3][t] = s2d;
  }
  __syncthreads();

  {  // A[table][hh][d]; thread t: d = t&127, two heads
    const int d = t & 127;
    const int h0 = (t >> 7) * 2;
#pragma unroll
    for (int hh = h0; hh < h0 + 2; ++hh) {
      const float* wk1 = Wk1 + hh * D * KD + d * KD;
      const float* wk2 = Wk2 + hh * D * KD + d * KD;
      float apq = 0.f, apo = 0.f, adp = 0.f, ado = 0.f;
#pragma unroll
      for (int k = 0; k < KD; ++k) {
        const float w1 = wk1[k], w2 = wk2[k];
        apq = fmaf(qq[0][hh * 32 + k], w1, apq);
        adp = fmaf(qq[2][hh * 32 + k], w1, adp);
        apo = fmaf(qq[1][hh * 32 + k], w2, apo);
        ado = fmaf(qq[3][hh * 32 + k], w2, ado);
      }
      sA[0][hh][d] = NORMF * apq;
      sA[1][hh][d] = NORMF * apo;
      sA[2][hh][d] = NORMF * adp;
      sA[3][hh][d] = NORMF * ado;
    }
  }
  __syncthreads();

  // Phase B: compat dots + fc1 decomposition
  const int gl = t & 63;
  const int hh = __builtin_amdgcn_readfirstlane(t >> 6);  // wave id == head
  const int g = g0 + gl;
  const float4* hg4 = (const float4*)(h + ((size_t)b * G + g) * D);
  const float4* hn4 = (const float4*)(h + ((size_t)b * G + rec[b * G + g]) * D);

  float cpp = 0.f, cpo = 0.f, cdp = 0.f, cdo = 0.f;
#pragma unroll 4
  for (int d4 = 0; d4 < 32; ++d4) {
    const float4 x = hg4[d4], y = hn4[d4];
    const float4 a1 = *(const float4*)&sA[0][hh][4 * d4];
    const float4 a2 = *(const float4*)&sA[1][hh][4 * d4];
    const float4 a3 = *(const float4*)&sA[2][hh][4 * d4];
    const float4 a4 = *(const float4*)&sA[3][hh][4 * d4];
    cpp = fmaf(x.x, a1.x, fmaf(x.y, a1.y, fmaf(x.z, a1.z, fmaf(x.w, a1.w, cpp))));
    cpo = fmaf(y.x, a2.x, fmaf(y.y, a2.y, fmaf(y.z, a2.z, fmaf(y.w, a2.w, cpo))));
    cdp = fmaf(x.x, a3.x, fmaf(x.y, a3.y, fmaf(x.z, a3.z, fmaf(x.w, a3.w, cdp))));
    cdo = fmaf(y.x, a4.x, fmaf(y.y, a4.y, fmaf(y.z, a4.z, fmaf(y.w, a4.w, cdo))));
  }
  sc[gl][hh] = cpp; sc[gl][4 + hh] = cpo; sc[gl][8 + hh] = cdp; sc[gl][12 + hh] = cdo;
  __syncthreads();

  float u[16];
#pragma unroll
  for (int i = 0; i < 16; ++i) u[i] = sc[gl][i];

  float pv[8], qv[8];
#pragma unroll
  for (int jj = 0; jj < 8; ++jj) {
    const int j = hh * 8 + jj;  // wave-uniform -> s_load weights
    float p = 0.f, q = fc1_b[j];
#pragma unroll
    for (int i = 0; i < 8; ++i) {
      p = fmaf(u[i], fc1_w[i * 32 + j], p);
      q = fmaf(u[8 + i], fc1_w[(8 + i) * 32 + j], q);
    }
    pv[jj] = p; qv[jj] = q;
  }

  // pack to fp16, transpose via LDS, coalesced uint stores
#pragma unroll
  for (int jj = 0; jj < 8; ++jj) sout[gl][hh * 8 + jj] = pv[jj];
  __syncthreads();
  {
    unsigned* dst = (unsigned*)((unsigned short*)ws + WS_P16H) +
                    ((size_t)b * G + g0) * 16;
#pragma unroll
    for (int i = t; i < 1024; i += 256) {
      const int row = i >> 4, c0 = (2 * i) & 31;
      __fp16 __attribute__((ext_vector_type(2))) pk =
          __builtin_amdgcn_cvt_pkrtz(sout[row][c0], sout[row][c0 + 1]);
      dst[i] = *(const unsigned*)&pk;
    }
  }
  __syncthreads();
#pragma unroll
  for (int jj = 0; jj < 8; ++jj) sout[gl][hh * 8 + jj] = qv[jj];
  __syncthreads();
  {
    unsigned* dst = (unsigned*)((unsigned short*)ws + WS_Q16H) +
                    ((size_t)b * G + g0) * 16;
#pragma unroll
    for (int i = t; i < 1024; i += 256) {
      const int row = i >> 4, c0 = (2 * i) & 31;
      __fp16 __attribute__((ext_vector_type(2))) pk =
          __builtin_amdgcn_cvt_pkrtz(sout[row][c0], sout[row][c0 + 1]);
      dst[i] = *(const unsigned*)&pk;
    }
  }
}

// ---------------- Stage 2: per-pair MLP via 32x32x16 f16 MFMA ----------------
// Grid (2,32,32); block 256 = 4 waves; wave w owns chunks {2w,2w+1} of 32 g2
// (cols w*64 + half*32). 16 g1 iterations; per iteration both chunks'
// form+MFMA issued before either epilogue (ILP). Epilogue: v_pk_max_f32 +
// v_pk_fma_f32 on acc pairs; one shfl_xor(32) reduces both chunks.
__global__ __launch_bounds__(256) void mlp_pairs(
    const float* __restrict__ ws,
    const float* __restrict__ fc2_w, const float* __restrict__ fc2_b,
    const float* __restrict__ fc3_w, const float* __restrict__ fc3_b,
    float* __restrict__ out) {
  const int b = blockIdx.z;
  const int g1_0 = blockIdx.y * 16;
  const int g2_0 = blockIdx.x * 256;
  const int t = threadIdx.x;
  const int w = t >> 6, l = t & 63;
  const int col = l & 31;   // pair within chunk
  const int half = l >> 5;  // k-subrange / n-subset selector
  const int kb = half * 8;

  __shared__ __align__(16) unsigned short sPh[16 * 32];  // 1 KB P tile
  {
    const unsigned* Psrc = (const unsigned*)((const unsigned short*)ws + WS_P16H) +
                           ((size_t)b * G + g1_0) * 16;
    ((unsigned*)sPh)[t] = Psrc[t];
  }

  // A-frags: W2t[n=col][k = kb+j] (f16 RTN); k-halves [0,16) / [16,32)
  v8h A0, A1;
#pragma unroll
  for (int j = 0; j < 8; ++j) {
    A0[j] = (_Float16)fc2_w[(kb + j) * 32 + col];
    A1[j] = (_Float16)fc2_w[(16 + kb + j) * 32 + col];
  }
  // Bias as C-seed; fc3 weights as packed pairs (n-mapped)
  v16f biasC;
  F2x8 w3p;
#pragma unroll
  for (int r = 0; r < 16; ++r) {
    const int n = (r & 3) + 8 * (r >> 2) + 4 * half;
    biasC[r] = fc2_b[n];
    ((float*)&w3p)[r] = fc3_w[n];
  }
  const float b3 = fc3_b[0];

  // Q fragments (g1-invariant, fp16) for both chunks
  HQ qlo[2], qhi[2];
#pragma unroll
  for (int c = 0; c < 2; ++c) {
    const unsigned short* qp = (const unsigned short*)ws + WS_Q16H +
        ((size_t)b * G + g2_0 + (2 * w + c) * 32 + col) * 32;
    qlo[c] = __builtin_bit_cast(HQ, *(const uint4*)(qp + kb));
    qhi[c] = __builtin_bit_cast(HQ, *(const uint4*)(qp + 16 + kb));
  }
  __syncthreads();

  const f2v z2 = {0.f, 0.f};
  float* op = out + (((size_t)b * G + g1_0) * G) + g2_0 + w * 64 + half * 32 + col;
#pragma unroll
  for (int g1 = 0; g1 < 16; ++g1) {
    const HQ plo = __builtin_bit_cast(HQ, *(const uint4*)(sPh + g1 * 32 + kb));
    const HQ phi = __builtin_bit_cast(HQ, *(const uint4*)(sPh + g1 * 32 + 16 + kb));

    // both chunks' B-frags + MFMA chains first (independent -> ILP)
    const v8h B0lo = relu_add(plo, qlo[0]);
    const v8h B0hi = relu_add(phi, qhi[0]);
    const v8h B1lo = relu_add(plo, qlo[1]);
    const v8h B1hi = relu_add(phi, qhi[1]);

    v16f acc0 = __builtin_amdgcn_mfma_f32_32x32x16_f16(A0, B0lo, biasC, 0, 0, 0);
    v16f acc1 = __builtin_amdgcn_mfma_f32_32x32x16_f16(A0, B1lo, biasC, 0, 0, 0);
    acc0 = __builtin_amdgcn_mfma_f32_32x32x16_f16(A1, B0hi, acc0, 0, 0, 0);
    acc1 = __builtin_amdgcn_mfma_f32_32x32x16_f16(A1, B1hi, acc1, 0, 0, 0);

    // packed-fp32 epilogue: 8 pk_max + 8 pk_fma per chunk
    const F2x8 f0 = __builtin_bit_cast(F2x8, acc0);
    const F2x8 f1 = __builtin_bit_cast(F2x8, acc1);
    f2v e0 = z2, e1 = z2;
#pragma unroll
    for (int i = 0; i < 8; ++i) {
      e0 = __builtin_elementwise_max(f0.v[i], z2) * w3p.v[i] + e0;
      e1 = __builtin_elementwise_max(f1.v[i], z2) * w3p.v[i] + e1;
    }
    const float sa = e0[0] + e0[1];
    const float sb = e1[0] + e1[1];

    // single-shuffle cross-half reduce serving both chunks:
    float y = half ? sb : sa;
    float zsw = half ? sa : sb;
    y += __shfl_xor(zsw, 32);
    // half0 lanes now hold chunk0 totals, half1 chunk1 -> contiguous store
    op[(size_t)g1 * G] = y + b3;
  }
}

extern "C" void kernel_launch(void* const* d_in, const int* in_sizes, int n_in,
                              void* d_out, int out_size, void* d_ws, size_t ws_size,
                              hipStream_t stream) {
  const float* h     = (const float*)d_in[0];
  const int*   pp    = (const int*)d_in[1];
  const int*   pd    = (const int*)d_in[2];
  const int*   rec   = (const int*)d_in[3];
  const float* Wq1   = (const float*)d_in[4];
  const float* Wk1   = (const float*)d_in[5];
  const float* Wq2   = (const float*)d_in[6];
  const float* Wk2   = (const float*)d_in[7];
  const float* fc1_w = (const float*)d_in[8];
  const float* fc1_b = (const float*)d_in[9];
  const float* fc2_w = (const float*)d_in[10];
  const float* fc2_b = (const float*)d_in[11];
  const float* fc3_w = (const float*)d_in[12];
  const float* fc3_b = (const float*)d_in[13];
  float* out = (float*)d_out;
  float* ws  = (float*)d_ws;

  stage01<<<dim3(256), dim3(256), 0, stream>>>(
      h, pp, pd, rec, Wq1, Wk1, Wq2, Wk2, fc1_w, fc1_b, ws);
  mlp_pairs<<<dim3(2, 32, 32), dim3(256), 0, stream>>>(
      ws, fc2_w, fc2_b, fc3_w, fc3_b, out);
}